// Round 3
// baseline (1307.652 us; speedup 1.0000x reference)
//
#include <hip/hip_runtime.h>
#include <cmath>

#define NH 2048
#define NI 96

// ---------------- GEMM: xin[b,t,:] = x[b,t,:] @ x2h  (no bias; bias added in seq kernel
// to match reference association order (xmul + smul) + bias) ----------------
__global__ __launch_bounds__(256) void xin_gemm(
    const float* __restrict__ A,
    const float* __restrict__ Bm,
    float* __restrict__ C)
{
    __shared__ float At[96][68];  // transposed A tile: At[k][r]
    __shared__ float Bt[96][68];  // Bt[k][c]
    const int tid = threadIdx.x;
    const int rowBase = blockIdx.y * 64;
    const int colBase = blockIdx.x * 64;

    {
        const int r = tid >> 2;
        const int sub = tid & 3;
        const float4* Arow = reinterpret_cast<const float4*>(A + (size_t)(rowBase + r) * NI);
        #pragma unroll
        for (int q = 0; q < 6; ++q) {
            const int k4 = sub + 4 * q;      // 0..23
            float4 v = Arow[k4];
            At[k4 * 4 + 0][r] = v.x;
            At[k4 * 4 + 1][r] = v.y;
            At[k4 * 4 + 2][r] = v.z;
            At[k4 * 4 + 3][r] = v.w;
        }
    }
    {
        const int c4 = tid & 15;
        const int k0 = tid >> 4;
        #pragma unroll
        for (int g = 0; g < 6; ++g) {
            const int kk = k0 + 16 * g;      // 0..95
            float4 v = *reinterpret_cast<const float4*>(Bm + (size_t)kk * NH + colBase + c4 * 4);
            *reinterpret_cast<float4*>(&Bt[kk][c4 * 4]) = v;
        }
    }
    __syncthreads();

    const int ty = tid >> 4, tx = tid & 15;
    float acc[4][4] = {};
    #pragma unroll 8
    for (int kk = 0; kk < 96; ++kk) {
        float4 a = *reinterpret_cast<const float4*>(&At[kk][ty * 4]);
        float4 b = *reinterpret_cast<const float4*>(&Bt[kk][tx * 4]);
        acc[0][0] += a.x * b.x; acc[0][1] += a.x * b.y; acc[0][2] += a.x * b.z; acc[0][3] += a.x * b.w;
        acc[1][0] += a.y * b.x; acc[1][1] += a.y * b.y; acc[1][2] += a.y * b.z; acc[1][3] += a.y * b.w;
        acc[2][0] += a.z * b.x; acc[2][1] += a.z * b.y; acc[2][2] += a.z * b.z; acc[2][3] += a.z * b.w;
        acc[3][0] += a.w * b.x; acc[3][1] += a.w * b.y; acc[3][2] += a.w * b.z; acc[3][3] += a.w * b.w;
    }
    #pragma unroll
    for (int i = 0; i < 4; ++i) {
        float4 o;
        o.x = acc[i][0]; o.y = acc[i][1]; o.z = acc[i][2]; o.w = acc[i][3];
        *reinterpret_cast<float4*>(C + (size_t)(rowBase + ty * 4 + i) * NH + colBase + tx * 4) = o;
    }
}

// ---------------- Sequential recurrence: one block per batch ----------------
// 512 threads; thread owns 4 neurons n0=4*tid .. n0+3.
// Phase-1 gather is a 4-stage rotated software pipeline (16 rows / 64 global
// loads in flight) to cover LLC latency; xin row is prefetched one full step
// ahead. Accumulation ORDER is bit-identical to the previous passing kernel:
// row at global list position k goes to accumulator a[k%4] for k < n4, and
// tail rows (k >= n4) fold into a0 in list order; reduce tree unchanged.
template <int USE_XIN>
__global__ __launch_bounds__(512) void esn_seq(
    const float* __restrict__ xin,   // [B*T*NH] (xmul only) if USE_XIN
    const float* __restrict__ x,     // [B*T*NI] for fallback
    const float* __restrict__ x2h,   // [NI*NH]
    const float* __restrict__ h2h,   // [NH*NH]
    const float* __restrict__ bias,  // [NH]
    float* __restrict__ out,         // [B*NH]
    int T)
{
    const int b = blockIdx.x;
    const int tid = threadIdx.x;
    const int n0 = tid * 4;
    const int wv = tid >> 6;
    const int lane = tid & 63;

    __shared__ alignas(16) int list[NH];
    __shared__ alignas(16) int wcnt[8];
    __shared__ float xt[NI];

    constexpr float DT = 0.075f;
    constexpr float TAU_M = 0.5f;
    constexpr float GGAMMA = 2.7f;
    constexpr float GEPS = 4.7f;
    constexpr float GAIN = 5.0f;
    const float ref_decay = expf(-0.075f / 0.25f);

    float lv[4] = {0.f, 0.f, 0.f, 0.f};
    float hy[4] = {0.f, 0.f, 0.f, 0.f};
    float hz[4] = {0.f, 0.f, 0.f, 0.f};
    float rf[4] = {0.f, 0.f, 0.f, 0.f};
    float cnt[4] = {0.f, 0.f, 0.f, 0.f};
    float bs[4];
    {
        const float4 b4 = *reinterpret_cast<const float4*>(&bias[n0]);
        bs[0] = b4.x; bs[1] = b4.y; bs[2] = b4.z; bs[3] = b4.w;
    }
    int nact = 0;

    if (!USE_XIN) {
        if (tid < NI) xt[tid] = x[(size_t)b * T * NI + tid];
    }
    __syncthreads();

    const unsigned long long below = (1ull << lane) - 1ull;
    const unsigned long long lo32 = 0xFFFFFFFFull;
    const unsigned long long mb = (lane >= 32) ? (below & ~lo32) : below;

    const float* __restrict__ xrow = USE_XIN ? (xin + (size_t)b * T * NH + n0) : xin;
    const int4* __restrict__ L4 = reinterpret_cast<const int4*>(list);

    // xin prefetch: xi always holds the CURRENT step's row, loaded one step early.
    float4 xi = make_float4(0.f, 0.f, 0.f, 0.f);
    if (USE_XIN) xi = *reinterpret_cast<const float4*>(xrow);

// pipeline stage macros: ISSUE reads 1 int4 of indices + 4 h2h rows (float4 each);
// ACC folds stage into accumulators with the fixed pos%4 -> a{0..3} mapping.
// NOTE: register names use W<St>_<j> so token pasting never abuts a pp-number
// ("W##St##0.x" would tokenize 0.x as one pp-number and fail to paste).
#define ISSUE(St, grp) do {                                                           \
        I##St = L4[(grp)];                                                            \
        W##St##_0 = *reinterpret_cast<const float4*>(&h2h[(size_t)I##St.x * NH + n0]); \
        W##St##_1 = *reinterpret_cast<const float4*>(&h2h[(size_t)I##St.y * NH + n0]); \
        W##St##_2 = *reinterpret_cast<const float4*>(&h2h[(size_t)I##St.z * NH + n0]); \
        W##St##_3 = *reinterpret_cast<const float4*>(&h2h[(size_t)I##St.w * NH + n0]); \
    } while (0)
#define ACC(St) do {                                                                  \
        a0[0] += W##St##_0.x; a0[1] += W##St##_0.y; a0[2] += W##St##_0.z; a0[3] += W##St##_0.w; \
        a1[0] += W##St##_1.x; a1[1] += W##St##_1.y; a1[2] += W##St##_1.z; a1[3] += W##St##_1.w; \
        a2[0] += W##St##_2.x; a2[1] += W##St##_2.y; a2[2] += W##St##_2.z; a2[3] += W##St##_2.w; \
        a3[0] += W##St##_3.x; a3[1] += W##St##_3.y; a3[2] += W##St##_3.z; a3[3] += W##St##_3.w; \
    } while (0)

    for (int t = 0; t < T; ++t) {
        // ---- issue next step's xin row first: consumed next iteration,
        // so its (possibly HBM) latency hides under this whole step.
        float4 xi_n;
        if (USE_XIN) {
            const int tn = (t + 1 < T) ? (t + 1) : t;
            xi_n = *reinterpret_cast<const float4*>(xrow + (size_t)tn * NH);
        }

        // ---- phase 1: pipelined gather over active rows (prev step's s)
        float a0[4] = {0.f, 0.f, 0.f, 0.f};
        float a1[4] = {0.f, 0.f, 0.f, 0.f};
        float a2[4] = {0.f, 0.f, 0.f, 0.f};
        float a3[4] = {0.f, 0.f, 0.f, 0.f};

        const int n4 = nact & ~3;
        const int G = n4 >> 2;            // full groups of 4 rows
        const int tc = nact - n4;         // tail rows (0..3)

        int4 I0, I1, I2, I3;
        float4 W0_0, W0_1, W0_2, W0_3;
        float4 W1_0, W1_1, W1_2, W1_3;
        float4 W2_0, W2_1, W2_2, W2_3;
        float4 W3_0, W3_1, W3_2, W3_3;

        // prologue: fill up to 4 stages + tail rows (all issued before any wait)
        if (0 < G) ISSUE(0, 0);
        if (1 < G) ISSUE(1, 1);
        if (2 < G) ISSUE(2, 2);
        if (3 < G) ISSUE(3, 3);
        float4 tw0, tw1, tw2;
        if (tc > 0) tw0 = *reinterpret_cast<const float4*>(&h2h[(size_t)list[n4] * NH + n0]);
        if (tc > 1) tw1 = *reinterpret_cast<const float4*>(&h2h[(size_t)list[n4 + 1] * NH + n0]);
        if (tc > 2) tw2 = *reinterpret_cast<const float4*>(&h2h[(size_t)list[n4 + 2] * NH + n0]);

        // steady state: consume 4 stages, refill 4 stages (indices read first)
        int g = 0;
        for (; g + 4 <= G; g += 4) {
            const bool r0 = (g + 4 < G), r1 = (g + 5 < G), r2 = (g + 6 < G), r3 = (g + 7 < G);
            ACC(0); if (r0) ISSUE(0, g + 4);
            ACC(1); if (r1) ISSUE(1, g + 5);
            ACC(2); if (r2) ISSUE(2, g + 6);
            ACC(3); if (r3) ISSUE(3, g + 7);
        }
        // drain remaining issued stages (G - g in 0..3)
        if (g + 0 < G) ACC(0);
        if (g + 1 < G) ACC(1);
        if (g + 2 < G) ACC(2);
        // tail rows fold into a0, in list order (bit-exact vs old scalar tail)
        if (tc > 0) { a0[0] += tw0.x; a0[1] += tw0.y; a0[2] += tw0.z; a0[3] += tw0.w; }
        if (tc > 1) { a0[0] += tw1.x; a0[1] += tw1.y; a0[2] += tw1.z; a0[3] += tw1.w; }
        if (tc > 2) { a0[0] += tw2.x; a0[1] += tw2.y; a0[2] += tw2.z; a0[3] += tw2.w; }

        float ic[4];
        if (USE_XIN) {
            const float xiv[4] = {xi.x, xi.y, xi.z, xi.w};
            #pragma unroll
            for (int c = 0; c < 4; ++c) {
                const float rec = (a0[c] + a1[c]) + (a2[c] + a3[c]);
                ic[c] = (xiv[c] + rec) + bs[c];
            }
            xi = xi_n;
        } else {
            float m[4] = {0.f, 0.f, 0.f, 0.f};
            for (int i = 0; i < NI; ++i) {
                const float xv = xt[i];
                const float4 w = *reinterpret_cast<const float4*>(&x2h[(size_t)i * NH + n0]);
                m[0] += xv * w.x; m[1] += xv * w.y; m[2] += xv * w.z; m[3] += xv * w.w;
            }
            #pragma unroll
            for (int c = 0; c < 4; ++c) {
                const float rec = (a0[c] + a1[c]) + (a2[c] + a3[c]);
                ic[c] = (m[c] + rec) + bs[c];
            }
        }

        // ---- LIF + RF oscillator (same expressions/order as previous kernel)
        float s[4];
        #pragma unroll
        for (int c = 0; c < 4; ++c) {
            lv[c] = lv[c] + DT * (-lv[c] / TAU_M + ic[c]);
            const float ls = lv[c] > 1.0f ? 1.0f : 0.0f;
            lv[c] -= ls;
            hz[c] = hz[c] + DT * ((GAIN * ls - GGAMMA * hy[c]) - GEPS * hz[c]);
            hy[c] = hy[c] + DT * hz[c];
            s[c] = ((hy[c] - 1.0f) - rf[c]) > 0.0f ? 1.0f : 0.0f;
            rf[c] = rf[c] * ref_decay + s[c];
            cnt[c] += s[c];
        }

        // ---- compaction ballots (deterministic, order-preserving)
        const unsigned long long ba = __ballot(s[0] > 0.0f);
        const unsigned long long bb = __ballot(s[1] > 0.0f);
        const unsigned long long bc = __ballot(s[2] > 0.0f);
        const unsigned long long bd = __ballot(s[3] > 0.0f);
        if (lane == 0)
            wcnt[wv] = (int)(__popcll(ba) + __popcll(bb) + __popcll(bc) + __popcll(bd));
        __syncthreads();   // list reads done; wcnt visible

        // ---- phase 2: cross-wave exclusive prefix (2 x int4 LDS reads)
        const int4 c0 = *reinterpret_cast<const int4*>(&wcnt[0]);
        const int4 c1 = *reinterpret_cast<const int4*>(&wcnt[4]);
        int pre = 0;
        pre += (wv > 0) ? c0.x : 0;
        pre += (wv > 1) ? c0.y : 0;
        pre += (wv > 2) ? c0.z : 0;
        pre += (wv > 3) ? c0.w : 0;
        pre += (wv > 4) ? c1.x : 0;
        pre += (wv > 5) ? c1.y : 0;
        pre += (wv > 6) ? c1.z : 0;
        const int tot = ((c0.x + c0.y) + (c0.z + c0.w)) + ((c1.x + c1.y) + (c1.z + c1.w));

        const int gaLo = (int)__popcll(ba & lo32);
        const int gbLo = (int)__popcll(bb & lo32);
        const int gcLo = (int)__popcll(bc & lo32);
        const int gdLo = (int)__popcll(bd & lo32);
        const int g0 = gaLo + gcLo;                                   // comps{0,2} lanes<32
        const int g1 = gbLo + gdLo;                                   // comps{1,3} lanes<32
        const int g2 = (int)(__popcll(ba) + __popcll(bc)) - g0;       // comps{0,2} lanes>=32
        const int base02 = (lane < 32) ? 0 : (g0 + g1);
        const int base13 = (lane < 32) ? g0 : ((g0 + g1) + g2);
        const int pa = (int)__popcll(ba & mb);
        const int pb = (int)__popcll(bb & mb);
        const int pc = (int)__popcll(bc & mb);
        const int pd = (int)__popcll(bd & mb);
        const int o02 = pre + base02 + pa + pc;
        const int o13 = pre + base13 + pb + pd;
        if (s[0] > 0.0f) list[o02] = n0;
        if (s[2] > 0.0f) list[o02 + (int)((ba >> lane) & 1ull)] = n0 + 2;
        if (s[1] > 0.0f) list[o13] = n0 + 1;
        if (s[3] > 0.0f) list[o13 + (int)((bb >> lane) & 1ull)] = n0 + 3;
        nact = tot;
        if (!USE_XIN) {
            if (t + 1 < T && tid < NI) xt[tid] = x[((size_t)b * T + (t + 1)) * NI + tid];
        }
        __syncthreads();   // list visible for next step
    }
#undef ISSUE
#undef ACC

    float4 o;
    o.x = cnt[0] / (float)T;
    o.y = cnt[1] / (float)T;
    o.z = cnt[2] / (float)T;
    o.w = cnt[3] / (float)T;
    *reinterpret_cast<float4*>(out + (size_t)b * NH + n0) = o;
}

extern "C" void kernel_launch(void* const* d_in, const int* in_sizes, int n_in,
                              void* d_out, int out_size, void* d_ws, size_t ws_size,
                              hipStream_t stream) {
    const float* x    = (const float*)d_in[0];   // [B,T,96]
    const float* x2h  = (const float*)d_in[1];   // [96,2048]
    const float* h2h  = (const float*)d_in[2];   // [2048,2048]
    const float* bias = (const float*)d_in[3];   // [2048]
    float* out = (float*)d_out;

    const int M = in_sizes[0] / NI;   // B*T
    const int T = 1024;
    const int B = M / T;

    const size_t xin_bytes = (size_t)M * NH * sizeof(float);
    if (ws_size >= xin_bytes) {
        float* xin = (float*)d_ws;
        dim3 grid(NH / 64, M / 64);
        xin_gemm<<<grid, 256, 0, stream>>>(x, x2h, xin);
        esn_seq<1><<<B, 512, 0, stream>>>(xin, x, x2h, h2h, bias, out, T);
    } else {
        esn_seq<0><<<B, 512, 0, stream>>>(x /*unused as xin*/, x, x2h, h2h, bias, out, T);
    }
}

// Round 4
// 1122.201 us; speedup vs baseline: 1.1653x; 1.1653x over previous
//
#include <hip/hip_runtime.h>
#include <cmath>

#define NH 2048
#define NI 96

// ---------------- GEMM: xin[b,t,:] = x[b,t,:] @ x2h  (no bias; bias added in seq kernel
// to match reference association order (xmul + smul) + bias) ----------------
__global__ __launch_bounds__(256) void xin_gemm(
    const float* __restrict__ A,
    const float* __restrict__ Bm,
    float* __restrict__ C)
{
    __shared__ float At[96][68];  // transposed A tile: At[k][r]
    __shared__ float Bt[96][68];  // Bt[k][c]
    const int tid = threadIdx.x;
    const int rowBase = blockIdx.y * 64;
    const int colBase = blockIdx.x * 64;

    {
        const int r = tid >> 2;
        const int sub = tid & 3;
        const float4* Arow = reinterpret_cast<const float4*>(A + (size_t)(rowBase + r) * NI);
        #pragma unroll
        for (int q = 0; q < 6; ++q) {
            const int k4 = sub + 4 * q;      // 0..23
            float4 v = Arow[k4];
            At[k4 * 4 + 0][r] = v.x;
            At[k4 * 4 + 1][r] = v.y;
            At[k4 * 4 + 2][r] = v.z;
            At[k4 * 4 + 3][r] = v.w;
        }
    }
    {
        const int c4 = tid & 15;
        const int k0 = tid >> 4;
        #pragma unroll
        for (int g = 0; g < 6; ++g) {
            const int kk = k0 + 16 * g;      // 0..95
            float4 v = *reinterpret_cast<const float4*>(Bm + (size_t)kk * NH + colBase + c4 * 4);
            *reinterpret_cast<float4*>(&Bt[kk][c4 * 4]) = v;
        }
    }
    __syncthreads();

    const int ty = tid >> 4, tx = tid & 15;
    float acc[4][4] = {};
    #pragma unroll 8
    for (int kk = 0; kk < 96; ++kk) {
        float4 a = *reinterpret_cast<const float4*>(&At[kk][ty * 4]);
        float4 b = *reinterpret_cast<const float4*>(&Bt[kk][tx * 4]);
        acc[0][0] += a.x * b.x; acc[0][1] += a.x * b.y; acc[0][2] += a.x * b.z; acc[0][3] += a.x * b.w;
        acc[1][0] += a.y * b.x; acc[1][1] += a.y * b.y; acc[1][2] += a.y * b.z; acc[1][3] += a.y * b.w;
        acc[2][0] += a.z * b.x; acc[2][1] += a.z * b.y; acc[2][2] += a.z * b.z; acc[2][3] += a.z * b.w;
        acc[3][0] += a.w * b.x; acc[3][1] += a.w * b.y; acc[3][2] += a.w * b.z; acc[3][3] += a.w * b.w;
    }
    #pragma unroll
    for (int i = 0; i < 4; ++i) {
        float4 o;
        o.x = acc[i][0]; o.y = acc[i][1]; o.z = acc[i][2]; o.w = acc[i][3];
        *reinterpret_cast<float4*>(C + (size_t)(rowBase + ty * 4 + i) * NH + colBase + tx * 4) = o;
    }
}

// ---------------- Sequential recurrence: one block per batch ----------------
// 512 threads; thread owns 4 neurons n0=4*tid .. n0+3.
// xin is staged through LDS in 4-step chunks (double-buffered, 64 KB): chunk
// c+1 is held in registers (loaded one boundary earlier, ~11k cycles of cover)
// and ds_written at the boundary of chunk c, so the per-step xin access is an
// LDS read hidden under the gather — no HBM latency on the per-step critical
// path, and no stale vmcnt entries blocking the gather's counted waits.
// Gather row indices are block-uniform -> readfirstlane to SGPR base (saddr
// loads, minimal VALU addressing). Accumulation ORDER is bit-identical to the
// previous passing kernel: row at global list position k -> a[k%4] for k<n4,
// tail rows fold into a0 in list order; reduce tree unchanged.
template <int USE_XIN>
__global__ __launch_bounds__(512) void esn_seq(
    const float* __restrict__ xin,   // [B*T*NH] (xmul only) if USE_XIN
    const float* __restrict__ x,     // [B*T*NI] for fallback
    const float* __restrict__ x2h,   // [NI*NH]
    const float* __restrict__ h2h,   // [NH*NH]
    const float* __restrict__ bias,  // [NH]
    float* __restrict__ out,         // [B*NH]
    int T)
{
    const int b = blockIdx.x;
    const int tid = threadIdx.x;
    const int n0 = tid * 4;
    const int wv = tid >> 6;
    const int lane = tid & 63;

    __shared__ alignas(16) int list[NH];
    __shared__ alignas(16) int wcnt[8];
    __shared__ float xt[NI];
    __shared__ alignas(16) float xstage[2][4][NH];   // 64 KB: 2 bufs x 4 steps

    constexpr float DT = 0.075f;
    constexpr float TAU_M = 0.5f;
    constexpr float GGAMMA = 2.7f;
    constexpr float GEPS = 4.7f;
    constexpr float GAIN = 5.0f;
    const float ref_decay = expf(-0.075f / 0.25f);

    float lv[4] = {0.f, 0.f, 0.f, 0.f};
    float hy[4] = {0.f, 0.f, 0.f, 0.f};
    float hz[4] = {0.f, 0.f, 0.f, 0.f};
    float rf[4] = {0.f, 0.f, 0.f, 0.f};
    float cnt[4] = {0.f, 0.f, 0.f, 0.f};
    float bs[4];
    {
        const float4 b4 = *reinterpret_cast<const float4*>(&bias[n0]);
        bs[0] = b4.x; bs[1] = b4.y; bs[2] = b4.z; bs[3] = b4.w;
    }
    int nact = 0;

    const float* __restrict__ xrow = USE_XIN ? (xin + (size_t)b * T * NH + n0) : xin;

    // chunk-staging registers: hold the NEXT chunk (4 rows) of this thread's
    // 4 xin columns; written to LDS at the next boundary.
    float4 P0, P1, P2, P3;

    if (USE_XIN) {
        // chunk 0 -> xstage[0] directly; issue chunk 1 -> P (no wait needed
        // until the t=3 boundary, ~4 steps away).
        #pragma unroll
        for (int r = 0; r < 4; ++r) {
            float4 v = *reinterpret_cast<const float4*>(xrow + (size_t)r * NH);
            *reinterpret_cast<float4*>(&xstage[0][r][n0]) = v;
        }
        P0 = *reinterpret_cast<const float4*>(xrow + (size_t)4 * NH);
        P1 = *reinterpret_cast<const float4*>(xrow + (size_t)5 * NH);
        P2 = *reinterpret_cast<const float4*>(xrow + (size_t)6 * NH);
        P3 = *reinterpret_cast<const float4*>(xrow + (size_t)7 * NH);
    } else {
        if (tid < NI) xt[tid] = x[(size_t)b * T * NI + tid];
    }
    __syncthreads();

    const unsigned long long below = (1ull << lane) - 1ull;
    const unsigned long long lo32 = 0xFFFFFFFFull;
    const unsigned long long mb = (lane >= 32) ? (below & ~lo32) : below;

    const int4* __restrict__ L4 = reinterpret_cast<const int4*>(list);

// pipeline stage macros: ISSUE reads 1 int4 of indices (block-uniform ->
// readfirstlane to SGPR base) + 4 h2h rows (float4 each); ACC folds the stage
// into accumulators with the fixed pos%4 -> a{0..3} mapping.
#define ISSUE(St, grp) do {                                                              \
        I##St = L4[(grp)];                                                               \
        const float* pr0 = h2h + (size_t)__builtin_amdgcn_readfirstlane(I##St.x) * NH;   \
        const float* pr1 = h2h + (size_t)__builtin_amdgcn_readfirstlane(I##St.y) * NH;   \
        const float* pr2 = h2h + (size_t)__builtin_amdgcn_readfirstlane(I##St.z) * NH;   \
        const float* pr3 = h2h + (size_t)__builtin_amdgcn_readfirstlane(I##St.w) * NH;   \
        W##St##_0 = *reinterpret_cast<const float4*>(pr0 + n0);                          \
        W##St##_1 = *reinterpret_cast<const float4*>(pr1 + n0);                          \
        W##St##_2 = *reinterpret_cast<const float4*>(pr2 + n0);                          \
        W##St##_3 = *reinterpret_cast<const float4*>(pr3 + n0);                          \
    } while (0)
#define ACC(St) do {                                                                  \
        a0[0] += W##St##_0.x; a0[1] += W##St##_0.y; a0[2] += W##St##_0.z; a0[3] += W##St##_0.w; \
        a1[0] += W##St##_1.x; a1[1] += W##St##_1.y; a1[2] += W##St##_1.z; a1[3] += W##St##_1.w; \
        a2[0] += W##St##_2.x; a2[1] += W##St##_2.y; a2[2] += W##St##_2.z; a2[3] += W##St##_2.w; \
        a3[0] += W##St##_3.x; a3[1] += W##St##_3.y; a3[2] += W##St##_3.z; a3[3] += W##St##_3.w; \
    } while (0)

    for (int t = 0; t < T; ++t) {
        // ---- current step's xin row: LDS read, hidden under the gather.
        float4 xi;
        if (USE_XIN) xi = *reinterpret_cast<const float4*>(&xstage[(t >> 2) & 1][t & 3][n0]);

        // ---- phase 1: pipelined gather over active rows (prev step's s)
        float a0[4] = {0.f, 0.f, 0.f, 0.f};
        float a1[4] = {0.f, 0.f, 0.f, 0.f};
        float a2[4] = {0.f, 0.f, 0.f, 0.f};
        float a3[4] = {0.f, 0.f, 0.f, 0.f};

        const int n4 = nact & ~3;
        const int G = n4 >> 2;            // full groups of 4 rows
        const int tc = nact - n4;         // tail rows (0..3)

        int4 I0, I1, I2, I3;
        float4 W0_0, W0_1, W0_2, W0_3;
        float4 W1_0, W1_1, W1_2, W1_3;
        float4 W2_0, W2_1, W2_2, W2_3;
        float4 W3_0, W3_1, W3_2, W3_3;

        // prologue: fill up to 4 stages + tail rows (all issued before any wait)
        if (0 < G) ISSUE(0, 0);
        if (1 < G) ISSUE(1, 1);
        if (2 < G) ISSUE(2, 2);
        if (3 < G) ISSUE(3, 3);
        float4 tw0, tw1, tw2;
        if (tc > 0) {
            const float* p = h2h + (size_t)__builtin_amdgcn_readfirstlane(list[n4]) * NH;
            tw0 = *reinterpret_cast<const float4*>(p + n0);
        }
        if (tc > 1) {
            const float* p = h2h + (size_t)__builtin_amdgcn_readfirstlane(list[n4 + 1]) * NH;
            tw1 = *reinterpret_cast<const float4*>(p + n0);
        }
        if (tc > 2) {
            const float* p = h2h + (size_t)__builtin_amdgcn_readfirstlane(list[n4 + 2]) * NH;
            tw2 = *reinterpret_cast<const float4*>(p + n0);
        }

        // steady state: consume 4 stages, refill 4 stages (indices read first)
        int g = 0;
        for (; g + 4 <= G; g += 4) {
            const bool r0 = (g + 4 < G), r1 = (g + 5 < G), r2 = (g + 6 < G), r3 = (g + 7 < G);
            ACC(0); if (r0) ISSUE(0, g + 4);
            ACC(1); if (r1) ISSUE(1, g + 5);
            ACC(2); if (r2) ISSUE(2, g + 6);
            ACC(3); if (r3) ISSUE(3, g + 7);
        }
        // drain remaining issued stages (G - g in 0..3)
        if (g + 0 < G) ACC(0);
        if (g + 1 < G) ACC(1);
        if (g + 2 < G) ACC(2);
        // tail rows fold into a0, in list order (bit-exact vs old scalar tail)
        if (tc > 0) { a0[0] += tw0.x; a0[1] += tw0.y; a0[2] += tw0.z; a0[3] += tw0.w; }
        if (tc > 1) { a0[0] += tw1.x; a0[1] += tw1.y; a0[2] += tw1.z; a0[3] += tw1.w; }
        if (tc > 2) { a0[0] += tw2.x; a0[1] += tw2.y; a0[2] += tw2.z; a0[3] += tw2.w; }

        float ic[4];
        if (USE_XIN) {
            const float xiv[4] = {xi.x, xi.y, xi.z, xi.w};
            #pragma unroll
            for (int c = 0; c < 4; ++c) {
                const float rec = (a0[c] + a1[c]) + (a2[c] + a3[c]);
                ic[c] = (xiv[c] + rec) + bs[c];
            }
        } else {
            float m[4] = {0.f, 0.f, 0.f, 0.f};
            for (int i = 0; i < NI; ++i) {
                const float xv = xt[i];
                const float4 w = *reinterpret_cast<const float4*>(&x2h[(size_t)i * NH + n0]);
                m[0] += xv * w.x; m[1] += xv * w.y; m[2] += xv * w.z; m[3] += xv * w.w;
            }
            #pragma unroll
            for (int c = 0; c < 4; ++c) {
                const float rec = (a0[c] + a1[c]) + (a2[c] + a3[c]);
                ic[c] = (m[c] + rec) + bs[c];
            }
        }

        // ---- LIF + RF oscillator (same expressions/order as previous kernel)
        float s[4];
        #pragma unroll
        for (int c = 0; c < 4; ++c) {
            lv[c] = lv[c] + DT * (-lv[c] / TAU_M + ic[c]);
            const float ls = lv[c] > 1.0f ? 1.0f : 0.0f;
            lv[c] -= ls;
            hz[c] = hz[c] + DT * ((GAIN * ls - GGAMMA * hy[c]) - GEPS * hz[c]);
            hy[c] = hy[c] + DT * hz[c];
            s[c] = ((hy[c] - 1.0f) - rf[c]) > 0.0f ? 1.0f : 0.0f;
            rf[c] = rf[c] * ref_decay + s[c];
            cnt[c] += s[c];
        }

        // ---- compaction ballots (deterministic, order-preserving)
        const unsigned long long ba = __ballot(s[0] > 0.0f);
        const unsigned long long bb = __ballot(s[1] > 0.0f);
        const unsigned long long bc = __ballot(s[2] > 0.0f);
        const unsigned long long bd = __ballot(s[3] > 0.0f);
        if (lane == 0)
            wcnt[wv] = (int)(__popcll(ba) + __popcll(bb) + __popcll(bc) + __popcll(bd));

        // ---- chunk boundary: commit next chunk (P, loaded 4 steps ago -> no
        // stall) into the other buffer; issue loads for the chunk after that.
        if (USE_XIN && ((t & 3) == 3)) {
            const int bufW = ((t >> 2) + 1) & 1;
            *reinterpret_cast<float4*>(&xstage[bufW][0][n0]) = P0;
            *reinterpret_cast<float4*>(&xstage[bufW][1][n0]) = P1;
            *reinterpret_cast<float4*>(&xstage[bufW][2][n0]) = P2;
            *reinterpret_cast<float4*>(&xstage[bufW][3][n0]) = P3;
            const int cNext = (t >> 2) + 2;
            if (cNext * 4 + 3 < T) {
                P0 = *reinterpret_cast<const float4*>(xrow + (size_t)(cNext * 4 + 0) * NH);
                P1 = *reinterpret_cast<const float4*>(xrow + (size_t)(cNext * 4 + 1) * NH);
                P2 = *reinterpret_cast<const float4*>(xrow + (size_t)(cNext * 4 + 2) * NH);
                P3 = *reinterpret_cast<const float4*>(xrow + (size_t)(cNext * 4 + 3) * NH);
            }
        }
        __syncthreads();   // list reads done; wcnt + staged xin visible

        // ---- phase 2: cross-wave exclusive prefix (2 x int4 LDS reads)
        const int4 c0 = *reinterpret_cast<const int4*>(&wcnt[0]);
        const int4 c1 = *reinterpret_cast<const int4*>(&wcnt[4]);
        int pre = 0;
        pre += (wv > 0) ? c0.x : 0;
        pre += (wv > 1) ? c0.y : 0;
        pre += (wv > 2) ? c0.z : 0;
        pre += (wv > 3) ? c0.w : 0;
        pre += (wv > 4) ? c1.x : 0;
        pre += (wv > 5) ? c1.y : 0;
        pre += (wv > 6) ? c1.z : 0;
        const int tot = ((c0.x + c0.y) + (c0.z + c0.w)) + ((c1.x + c1.y) + (c1.z + c1.w));

        const int gaLo = (int)__popcll(ba & lo32);
        const int gbLo = (int)__popcll(bb & lo32);
        const int gcLo = (int)__popcll(bc & lo32);
        const int gdLo = (int)__popcll(bd & lo32);
        const int g0 = gaLo + gcLo;                                   // comps{0,2} lanes<32
        const int g1 = gbLo + gdLo;                                   // comps{1,3} lanes<32
        const int g2 = (int)(__popcll(ba) + __popcll(bc)) - g0;       // comps{0,2} lanes>=32
        const int base02 = (lane < 32) ? 0 : (g0 + g1);
        const int base13 = (lane < 32) ? g0 : ((g0 + g1) + g2);
        const int pa = (int)__popcll(ba & mb);
        const int pb = (int)__popcll(bb & mb);
        const int pc = (int)__popcll(bc & mb);
        const int pd = (int)__popcll(bd & mb);
        const int o02 = pre + base02 + pa + pc;
        const int o13 = pre + base13 + pb + pd;
        if (s[0] > 0.0f) list[o02] = n0;
        if (s[2] > 0.0f) list[o02 + (int)((ba >> lane) & 1ull)] = n0 + 2;
        if (s[1] > 0.0f) list[o13] = n0 + 1;
        if (s[3] > 0.0f) list[o13 + (int)((bb >> lane) & 1ull)] = n0 + 3;
        nact = tot;
        if (!USE_XIN) {
            if (t + 1 < T && tid < NI) xt[tid] = x[((size_t)b * T + (t + 1)) * NI + tid];
        }
        __syncthreads();   // list visible for next step
    }
#undef ISSUE
#undef ACC

    float4 o;
    o.x = cnt[0] / (float)T;
    o.y = cnt[1] / (float)T;
    o.z = cnt[2] / (float)T;
    o.w = cnt[3] / (float)T;
    *reinterpret_cast<float4*>(out + (size_t)b * NH + n0) = o;
}

extern "C" void kernel_launch(void* const* d_in, const int* in_sizes, int n_in,
                              void* d_out, int out_size, void* d_ws, size_t ws_size,
                              hipStream_t stream) {
    const float* x    = (const float*)d_in[0];   // [B,T,96]
    const float* x2h  = (const float*)d_in[1];   // [96,2048]
    const float* h2h  = (const float*)d_in[2];   // [2048,2048]
    const float* bias = (const float*)d_in[3];   // [2048]
    float* out = (float*)d_out;

    const int M = in_sizes[0] / NI;   // B*T
    const int T = 1024;
    const int B = M / T;

    const size_t xin_bytes = (size_t)M * NH * sizeof(float);
    if (ws_size >= xin_bytes) {
        float* xin = (float*)d_ws;
        dim3 grid(NH / 64, M / 64);
        xin_gemm<<<grid, 256, 0, stream>>>(x, x2h, xin);
        esn_seq<1><<<B, 512, 0, stream>>>(xin, x, x2h, h2h, bias, out, T);
    } else {
        esn_seq<0><<<B, 512, 0, stream>>>(x /*unused as xin*/, x, x2h, h2h, bias, out, T);
    }
}